// Round 13
// baseline (232.937 us; speedup 1.0000x reference)
//
#include <hip/hip_runtime.h>

// PixelPropagationModule  out = gamma * (softmax(qk^T) @ v^T)^T + x
// B=8, C=256, CI=64, N=3136 (56x56), fp32 in/out.
// R17: JS=1 fusion with TWO-SEGMENT pipeline. R16 post-mortem: 49-step
//      full unroll -> address-hoisting live-range explosion (VGPR 256,
//      occupancy 0.4-8%, attn 132us). Fix: same fused kernel (no reduce,
//      no partials, in-block finalize) but the 49 j-steps run as two
//      sequential pipelined segments of 25 and 24 steps -- exactly the
//      unroll size that compiled to VGPR 112 in R14. Each segment has its
//      own prologue (V0,V1,K0 in flight -> vmcnt(8) -> commit) and epilogue
//      (vmcnt(4)/(0)); one extra BAR between segments (vs[0] readers must
//      finish before segment 2's commit). O/lsum accumulate in-register
//      across segments. proj/weights = R14.

constexpr int B_  = 8;
constexpr int C_  = 256;
constexpr int CI_ = 64;
constexpr int N_  = 3136;
constexpr int JT  = 32;       // attn j per step
constexpr int VSP = 40;       // V LDS row pitch (ushorts) = 80 B (16B-aligned)
constexpr int PN  = 64;       // proj pixel tile
constexpr int XSP = C_ + 8;   // proj LDS row pitch

typedef __attribute__((ext_vector_type(8))) short short8;   // 8 bf16 (4 VGPR)
typedef __attribute__((ext_vector_type(4))) float f32x4;
typedef __attribute__((ext_vector_type(4))) ushort us4;

static __device__ inline ushort f2b(float f) {               // fp32 -> bf16 (RNE)
    unsigned u = __float_as_uint(f);
    return (ushort)((u + 0x7fffu + ((u >> 16) & 1u)) >> 16);
}
static __device__ inline float b2f(ushort h) {
    return __uint_as_float(((unsigned)h) << 16);
}

// grid 256: Wq/Wk -> wqk[128][256], Wv -> wv[256][256] bf16
__global__ __launch_bounds__(256)
void weights_kernel(const float* __restrict__ Wq, const float* __restrict__ Wk,
                    const float* __restrict__ Wv,
                    ushort* __restrict__ wqk, ushort* __restrict__ wv)
{
    int i = blockIdx.x * 256 + threadIdx.x;
    if (i < 16384)      wqk[i] = f2b(Wq[i]);
    else if (i < 32768) wqk[i] = f2b(Wk[i - 16384]);
    wv[i] = f2b(Wv[i]);
}

// grid B_*49: block (b, 64-pixel tile). Transposes x[b,:,n0..n0+64] fp32
// into xs[64][256] bf16 in LDS (phase 1), then QK / V projection GEMMs.
__global__ __launch_bounds__(256)
void proj_kernel(const float* __restrict__ x, const ushort* __restrict__ wqk,
                 const ushort* __restrict__ wv,
                 const float* __restrict__ bq, const float* __restrict__ bk,
                 const float* __restrict__ bv,
                 ushort* __restrict__ qb, ushort* __restrict__ kb, ushort* __restrict__ vt)
{
    __shared__ __align__(16) ushort xs[PN][XSP];     // 33792 B
    const int b   = blockIdx.x / 49;
    const int n0  = (blockIdx.x % 49) * PN;
    const int tid = threadIdx.x;
    const int w    = tid >> 6;
    const int lane = tid & 63;
    const int m16  = lane & 15;
    const int quad = lane >> 4;

    // ---- transpose-in: 8 reps x (256 thr x 8 floats) = 64n x 256c ----
    {
        const float* xsrc = x + (size_t)b * C_ * N_ + n0;
        #pragma unroll
        for (int rep = 0; rep < 8; rep++) {
            const int u = rep * 4 + w;               // c8-group 0..31
            short8 v;
            #pragma unroll
            for (int j = 0; j < 8; j++)
                v[j] = (short)f2b(xsrc[(size_t)(u * 8 + j) * N_ + lane]);
            *(short8*)&xs[lane][u * 8] = v;
        }
    }
    __syncthreads();

    // ---- QK GEMM: C[o][pixel]; waves 0,1 -> Q halves, 2,3 -> K halves ----
    {
        f32x4 acc[2][4];
        #pragma unroll
        for (int mt = 0; mt < 2; mt++)
            #pragma unroll
            for (int nt = 0; nt < 4; nt++) acc[mt][nt] = (f32x4){0.f, 0.f, 0.f, 0.f};

        #pragma unroll
        for (int kk = 0; kk < 8; kk++) {
            short8 af[2];
            #pragma unroll
            for (int mt = 0; mt < 2; mt++)   // A[m=o][k=c] = wqk row (L2-hot)
                af[mt] = *(const short8*)(wqk + (size_t)(w * 32 + mt * 16 + m16) * C_ + kk * 32 + quad * 8);
            #pragma unroll
            for (int nt = 0; nt < 4; nt++) {
                short8 bf = *(const short8*)&xs[nt * 16 + m16][kk * 32 + quad * 8];  // B[k=c][n=pix]
                #pragma unroll
                for (int mt = 0; mt < 2; mt++)
                    acc[mt][nt] = __builtin_amdgcn_mfma_f32_16x16x32_bf16(af[mt], bf, acc[mt][nt], 0, 0, 0);
            }
        }
        const float* bias = (w < 2) ? bq : bk;
        ushort* dst = (w < 2) ? qb : kb;
        const int obase = (w & 1) * 32;
        #pragma unroll
        for (int mt = 0; mt < 2; mt++) {
            f32x4 bs = *(const f32x4*)(bias + obase + mt * 16 + quad * 4);
            #pragma unroll
            for (int nt = 0; nt < 4; nt++) {
                us4 pk;
                pk.x = f2b(acc[mt][nt][0] + bs[0]);
                pk.y = f2b(acc[mt][nt][1] + bs[1]);
                pk.z = f2b(acc[mt][nt][2] + bs[2]);
                pk.w = f2b(acc[mt][nt][3] + bs[3]);
                *(us4*)(dst + ((size_t)b * N_ + n0 + nt * 16 + m16) * CI_ + obase + mt * 16 + quad * 4) = pk;
            }
        }
    }

    // ---- V GEMM: C[pixel][o]; wave w -> channels w*64..w*64+63 ----
    {
        f32x4 vacc[4][4];
        #pragma unroll
        for (int mt = 0; mt < 4; mt++)
            #pragma unroll
            for (int nt = 0; nt < 4; nt++) vacc[mt][nt] = (f32x4){0.f, 0.f, 0.f, 0.f};

        #pragma unroll
        for (int kk = 0; kk < 8; kk++) {
            short8 af[4];
            #pragma unroll
            for (int mt = 0; mt < 4; mt++)   // A[m=pix][k=c] from LDS
                af[mt] = *(const short8*)&xs[mt * 16 + m16][kk * 32 + quad * 8];
            #pragma unroll
            for (int nt = 0; nt < 4; nt++) {
                short8 bf = *(const short8*)(wv + (size_t)(w * 64 + nt * 16 + m16) * C_ + kk * 32 + quad * 8);
                #pragma unroll
                for (int mt = 0; mt < 4; mt++)
                    vacc[mt][nt] = __builtin_amdgcn_mfma_f32_16x16x32_bf16(af[mt], bf, vacc[mt][nt], 0, 0, 0);
            }
        }
        #pragma unroll
        for (int nt = 0; nt < 4; nt++) {
            int c = w * 64 + nt * 16 + m16;
            float bvc = bv[c];
            #pragma unroll
            for (int mt = 0; mt < 4; mt++) {
                us4 pk;
                pk.x = f2b(vacc[mt][nt][0] + bvc);
                pk.y = f2b(vacc[mt][nt][1] + bvc);
                pk.z = f2b(vacc[mt][nt][2] + bvc);
                pk.w = f2b(vacc[mt][nt][3] + bvc);
                *(us4*)(vt + ((size_t)b * C_ + c) * N_ + n0 + mt * 16 + quad * 4) = pk;
            }
        }
    }
}

// grid B_*49 = 392. XCD swizzle: b = bx&7; t = bx>>3 (0..48). Wave w:
// queries t*64+w*16, all 256 channels, FULL j-range as two pipelined
// segments (25 + 24 steps of 32). Pinned asm loads + manual vmcnt per
// segment (R14-proven 25/24-step unroll size -> VGPR ~112, no hoist blow).
// Epilogue: l and O complete in-register -> out = gamma*O/l + x directly.
__global__ __launch_bounds__(256)
void attn_kernel(const ushort* __restrict__ qb, const ushort* __restrict__ kb,
                 const ushort* __restrict__ vt,
                 const float* __restrict__ x, const float* __restrict__ gamma_p,
                 float* __restrict__ out)
{
    __shared__ __align__(16) ushort vs[2][C_][VSP];  // 40960 B (4 blocks/CU)

    const int bx   = blockIdx.x;
    const int b    = bx & 7;            // XCD-local batch
    const int t    = bx >> 3;           // 0..48
    const int tid  = threadIdx.x;
    const int w    = tid >> 6;
    const int lane = tid & 63;
    const int m16  = lane & 15;
    const int quad = lane >> 4;
    const int i0   = t * 64 + w * 16;

    const ushort* vtb = vt + (size_t)b * C_ * N_;
    const ushort* kbb = kb + (size_t)b * N_ * CI_;

    f32x4 O[16];
    #pragma unroll
    for (int ct = 0; ct < 16; ct++) O[ct] = (f32x4){0.f, 0.f, 0.f, 0.f};
    float lsum = 0.f;

    // staging: thread -> c row (4 thr/row), 16B global segment seg
    const int sc  = tid >> 2;
    const int seg = tid & 3;
    const int p0  = (seg & 1) * 16 + (seg >> 1) * 4;     // permuted dest base

    const ushort* vbase[4];
    #pragma unroll
    for (int p = 0; p < 4; p++)
        vbase[p] = vtb + (size_t)(p * 64 + sc) * N_ + seg * 8;

    short8 qf[2];                 // Q B-frags (loaded once)
    short8 pr[2][4];              // V prefetch, 2-deep (parity-indexed, static)
    short8 kr[2][4];              // K prefetch, 1-deep (parity-indexed, static)

    #define GLOAD(DST, ADDR)                                                   \
        asm volatile("global_load_dwordx4 %0, %1, off"                         \
                     : "=v"(DST) : "v"(ADDR));
    #define GPREFETCH(PR, J0)                                                  \
        {                                                                      \
            _Pragma("unroll")                                                  \
            for (int p = 0; p < 4; p++) {                                      \
                const ushort* a_ = vbase[p] + (J0);                            \
                GLOAD(PR[p], a_)                                               \
            }                                                                  \
        }
    #define GKLOAD(J0, KR)                                                     \
        {                                                                      \
            _Pragma("unroll")                                                  \
            for (int h = 0; h < 2; h++) {                                      \
                const ushort* krow = kbb + (size_t)((J0) + h * 16 + m16) * CI_; \
                const ushort* a0_ = krow + quad * 8;                           \
                const ushort* a1_ = krow + 32 + quad * 8;                      \
                GLOAD(KR[2 * h], a0_)                                          \
                GLOAD(KR[2 * h + 1], a1_)                                      \
            }                                                                  \
        }
    #define COMMIT(PR, BUF)                                                    \
        {                                                                      \
            _Pragma("unroll")                                                  \
            for (int p = 0; p < 4; p++) {                                      \
                *(us4*)&vs[BUF][p * 64 + sc][p0]     = ((const us4*)&PR[p])[0]; \
                *(us4*)&vs[BUF][p * 64 + sc][p0 + 8] = ((const us4*)&PR[p])[1]; \
            }                                                                  \
        }
    #define VWAIT(N)                                                           \
        {                                                                      \
            asm volatile("s_waitcnt vmcnt(" #N ")" ::: "memory");              \
            __builtin_amdgcn_sched_barrier(0);                                 \
        }
    // lgkm-only barrier: commits visible, global loads stay outstanding.
    #define BAR()                                                              \
        {                                                                      \
            __builtin_amdgcn_sched_barrier(0);                                 \
            asm volatile("s_waitcnt lgkmcnt(0)" ::: "memory");                 \
            __builtin_amdgcn_sched_barrier(0);                                 \
            __builtin_amdgcn_s_barrier();                                      \
            __builtin_amdgcn_sched_barrier(0);                                 \
        }
    // QK (S^T = K Q^T) -> exp -> pa ; PV over all 256 ch from vs[CUR]
    #define COMPUTE(CUR, KRC)                                                  \
        {                                                                      \
            short8 pa;                                                         \
            _Pragma("unroll")                                                  \
            for (int h = 0; h < 2; h++) {                                      \
                f32x4 T = (f32x4){0.f, 0.f, 0.f, 0.f};                         \
                T = __builtin_amdgcn_mfma_f32_16x16x32_bf16(KRC[2 * h],     qf[0], T, 0, 0, 0); \
                T = __builtin_amdgcn_mfma_f32_16x16x32_bf16(KRC[2 * h + 1], qf[1], T, 0, 0, 0); \
                _Pragma("unroll")                                              \
                for (int r = 0; r < 4; r++) {                                  \
                    float pv = __expf(T[r] - 12.0f);   /* static shift */      \
                    lsum += pv;                                                \
                    pa[h * 4 + r] = (short)f2b(pv);                            \
                }                                                              \
            }                                                                  \
            __builtin_amdgcn_s_setprio(1);                                     \
            _Pragma("unroll")                                                  \
            for (int ct = 0; ct < 16; ct++) {                                  \
                short8 vf = *(const short8*)&vs[CUR][ct * 16 + m16][quad * 8]; \
                O[ct] = __builtin_amdgcn_mfma_f32_16x16x32_bf16(pa, vf, O[ct], 0, 0, 0); \
            }                                                                  \
            __builtin_amdgcn_s_setprio(0);                                     \
        }
    // Segment prologue: V(0),V(1),K(0) of this segment in flight; vmcnt(8)
    // leaves exactly {V(1),K(0)}=8 outstanding (retires pr[0] (+qf if 1st)).
    #define SEGPRO(JB)                                                         \
        GPREFETCH(pr[0], JB)                                                   \
        GPREFETCH(pr[1], (JB) + JT)                                            \
        GKLOAD(JB, kr[0])                                                      \
        VWAIT(8)                                                               \
        COMMIT(pr[0], 0)                                                       \
        BAR()
    // Segment body: R14-proven unroll. Last step ends DRAINED (vmcnt(0)),
    // no trailing commit/BAR.
    #define SEGRUN(JB, STEPS_)                                                 \
        _Pragma("unroll")                                                      \
        for (int st = 0; st < (STEPS_); ++st) {                                \
            const int cur = st & 1;                                            \
            const int j0_ = (JB) + st * JT;                                    \
            if (st + 2 < (STEPS_)) GPREFETCH(pr[cur], j0_ + 2 * JT)            \
            if (st + 1 < (STEPS_)) GKLOAD(j0_ + JT, kr[cur ^ 1])               \
            if (st + 2 < (STEPS_)) { VWAIT(8) }                                \
            else if (st + 1 < (STEPS_)) { VWAIT(4) }                           \
            else { VWAIT(0) }                                                  \
            COMPUTE(cur, kr[cur])                                              \
            if (st + 1 < (STEPS_)) {                                           \
                COMMIT(pr[cur ^ 1], cur ^ 1)                                   \
                BAR()                                                          \
            }                                                                  \
        }

    // ---- segment 1: j in [0, 800) ----
    {
        const ushort* qbase = qb + ((size_t)b * N_ + i0 + m16) * CI_;
        const ushort* qa0 = qbase + quad * 8;
        const ushort* qa1 = qbase + 32 + quad * 8;
        GLOAD(qf[0], qa0)
        GLOAD(qf[1], qa1)
    }
    SEGPRO(0)                       // 14 outstanding -> vmcnt(8) retires qf+V(0)
    SEGRUN(0, 25)                   // ends drained, last read of vs[0]

    // ---- segment 2: j in [800, 1568) ----
    BAR()                           // all waves done reading vs[0]
    SEGPRO(25 * JT)                 // 12 outstanding -> vmcnt(8) retires V(0)
    SEGRUN(25 * JT, 24)

    // ---- finalize in-block: out = gamma*O/l + x (l complete: JS=1) ----
    {
        float v = lsum;
        v += __shfl_xor(v, 16);
        v += __shfl_xor(v, 32);      // all lanes: total l for query i0+m16

        const float g0 = gamma_p[0];
        f32x4 inv;
        #pragma unroll
        for (int r = 0; r < 4; r++) {
            // O rows are queries i0+quad*4+r; their l lives in lane quad*4+r
            float lr = __shfl(v, quad * 4 + r);
            inv[r] = g0 / lr;
        }
        const float* xb = x + (size_t)b * C_ * N_;
        float* ob = out + (size_t)b * C_ * N_;
        #pragma unroll
        for (int ct = 0; ct < 16; ct++) {
            const size_t ro = (size_t)(ct * 16 + m16) * N_ + i0 + quad * 4;
            f32x4 xv = *(const f32x4*)(xb + ro);
            f32x4 ov;
            #pragma unroll
            for (int r = 0; r < 4; r++)
                ov[r] = O[ct][r] * inv[r] + xv[r];
            *(f32x4*)(ob + ro) = ov;
        }
    }
    #undef GLOAD
    #undef GPREFETCH
    #undef GKLOAD
    #undef COMMIT
    #undef VWAIT
    #undef BAR
    #undef COMPUTE
    #undef SEGPRO
    #undef SEGRUN
}

extern "C" void kernel_launch(void* const* d_in, const int* in_sizes, int n_in,
                              void* d_out, int out_size, void* d_ws, size_t ws_size,
                              hipStream_t stream)
{
    const float* x  = (const float*)d_in[0];
    const float* Wq = (const float*)d_in[1];
    const float* bq = (const float*)d_in[2];
    const float* Wk = (const float*)d_in[3];
    const float* bk = (const float*)d_in[4];
    const float* Wv = (const float*)d_in[5];
    const float* bv = (const float*)d_in[6];
    const float* gm = (const float*)d_in[7];
    float* out = (float*)d_out;

    ushort* qb   = (ushort*)d_ws;                    // [B][N][CI]  3.2 MB
    ushort* kb   = qb + (size_t)B_ * N_ * CI_;       // [B][N][CI]  3.2 MB
    ushort* vt   = kb + (size_t)B_ * N_ * CI_;       // [B][C][N]  12.8 MB
    ushort* wqk  = vt + (size_t)B_ * C_ * N_;        // [128][256] 64 KB
    ushort* wv   = wqk + 128 * C_;                   // [256][256] 128 KB

    hipLaunchKernelGGL(weights_kernel, dim3(256), dim3(256), 0, stream,
                       Wq, Wk, Wv, wqk, wv);
    hipLaunchKernelGGL(proj_kernel, dim3(B_ * 49), dim3(256), 0, stream,
                       x, wqk, wv, bq, bk, bv, qb, kb, vt);
    hipLaunchKernelGGL(attn_kernel, dim3(B_ * 49), dim3(256), 0, stream,
                       qb, kb, vt, x, gm, out);
}